// Round 10
// baseline (4166.957 us; speedup 1.0000x reference)
//
#include <hip/hip_runtime.h>
#include <hip/hip_bf16.h>
#include <math.h>

#define BATCH 128
#define SEQ   512
#define IND   512
#define F     1024
#define OUTD  256
// concat K = F + IND = 1536
#define KC    1536
#define N3    3072

typedef __bf16 v8bf __attribute__((ext_vector_type(8)));
typedef float  v4f  __attribute__((ext_vector_type(4)));
typedef unsigned short u16;
typedef u16 v8u __attribute__((ext_vector_type(8)));
typedef unsigned long long u64t;

// packed tile layout, shared by x and h:
//   [chunk][plane 2][mt 2][lane 64][8 elems]  (2048 elems per chunk)
// lane = q*16 + l15 maps to (row = mt*16 + l15, cols = chunk*32 + q*8 .. +7)

__device__ inline u16 f2bf(float x) {
    union { float f; unsigned u; } v; v.f = x;
    unsigned r = v.u + 0x7fff + ((v.u >> 16) & 1);
    return (u16)(r >> 16);
}
__device__ inline float bf2f(u16 h) {
    union { unsigned u; float f; } v; v.u = ((unsigned)h) << 16;
    return v.f;
}

__device__ inline float sigm(float x) { return 1.f / (1.f + __expf(-x)); }
__device__ inline float tanh_fast(float x) {
    float xc = fminf(fmaxf(x, -15.f), 15.f);
    float e = __expf(2.f * xc);
    return (e - 1.f) / (e + 1.f);
}

// ---------------- prep: inputs [B][T][I] fp32 -> packed x tiles ----------------
// xpk[t][gb][chunk 0..15][plane][mt][lane][8]
__global__ void k_prep_x(const float* __restrict__ in, u16* __restrict__ xpk) {
    int gid = blockIdx.x * 256 + threadIdx.x;     // 4,194,304 chunks of 8
    int b = gid >> 15;
    int rem = gid & 32767;
    int t = rem >> 6;
    int c = rem & 63;                              // 8-col segment index
    const float* s = in + (size_t)gid * 8;
    float4 a0 = ((const float4*)s)[0];
    float4 a1 = ((const float4*)s)[1];
    float a[8] = {a0.x, a0.y, a0.z, a0.w, a1.x, a1.y, a1.z, a1.w};
    v8u oh, ol;
    #pragma unroll
    for (int i = 0; i < 8; i++) {
        u16 h = f2bf(a[i]);
        oh[i] = h;
        ol[i] = f2bf(a[i] - bf2f(h));
    }
    int gb = b >> 5, mt = (b >> 4) & 1, l15 = b & 15;
    int chunk = c >> 2, q = c & 3;
    int lane = q * 16 + l15;
    size_t base = ((size_t)(t * 4 + gb) * 16 + chunk) * 2048 + mt * 512 + lane * 8;
    *(v8u*)(xpk + base) = oh;            // plane 0 (hi)
    *(v8u*)(xpk + base + 1024) = ol;     // plane 1 (lo)
}

// ------------- prep: WcT[n][k] hi/lo bf16 planes, n in [0,3072), k in [0,1536) --------------
__global__ void k_prep_w(const float* __restrict__ Wi, const float* __restrict__ Wh,
                         u16* __restrict__ Whi, u16* __restrict__ Wlo) {
    __shared__ float lds[32][33];
    int nb = blockIdx.x % 96;      // 3072/32
    int kb = blockIdx.x / 96;      // 1536/32
    int tid = threadIdx.x;
    int n_l = tid & 31, kr = tid >> 5;
    #pragma unroll
    for (int j = 0; j < 4; j++) {
        int k_l = kr + j * 8;
        int k = kb * 32 + k_l, n = nb * 32 + n_l;
        float v = (k < F) ? Wh[(size_t)k * N3 + n] : Wi[(size_t)(k - F) * N3 + n];
        lds[k_l][n_l] = v;
    }
    __syncthreads();
    int k_l2 = tid & 31, nr = tid >> 5;
    #pragma unroll
    for (int j = 0; j < 4; j++) {
        int n_l2 = nr + j * 8;
        float v = lds[k_l2][n_l2];
        u16 h = f2bf(v);
        size_t off = (size_t)(nb * 32 + n_l2) * KC + kb * 32 + k_l2;
        Whi[off] = h;
        Wlo[off] = f2bf(v - bf2f(h));
    }
}

// one K-chunk: 18 MFMAs = 3 gates x 2 m-tiles x 3 products (Ah*Bh + Ah*Bl + Al*Bh)
// all operands in registers (lo-plane weights moved out of LDS in round 10)
template<int G2>
__device__ __forceinline__ void do_chunk(v8bf a0h, v8bf a1h, v8bf a0l, v8bf a1l,
                                         v8bf w0h, v8bf w1h, v8bf w2h,
                                         v8bf w0l, v8bf w1l, v8bf w2l,
                                         v4f (&acc)[4][2]) {
    acc[0][0]  = __builtin_amdgcn_mfma_f32_16x16x32_bf16(a0h, w0h, acc[0][0], 0, 0, 0);
    acc[0][1]  = __builtin_amdgcn_mfma_f32_16x16x32_bf16(a1h, w0h, acc[0][1], 0, 0, 0);
    acc[1][0]  = __builtin_amdgcn_mfma_f32_16x16x32_bf16(a0h, w1h, acc[1][0], 0, 0, 0);
    acc[1][1]  = __builtin_amdgcn_mfma_f32_16x16x32_bf16(a1h, w1h, acc[1][1], 0, 0, 0);
    acc[G2][0] = __builtin_amdgcn_mfma_f32_16x16x32_bf16(a0h, w2h, acc[G2][0], 0, 0, 0);
    acc[G2][1] = __builtin_amdgcn_mfma_f32_16x16x32_bf16(a1h, w2h, acc[G2][1], 0, 0, 0);
    acc[0][0]  = __builtin_amdgcn_mfma_f32_16x16x32_bf16(a0h, w0l, acc[0][0], 0, 0, 0);
    acc[0][1]  = __builtin_amdgcn_mfma_f32_16x16x32_bf16(a1h, w0l, acc[0][1], 0, 0, 0);
    acc[1][0]  = __builtin_amdgcn_mfma_f32_16x16x32_bf16(a0h, w1l, acc[1][0], 0, 0, 0);
    acc[1][1]  = __builtin_amdgcn_mfma_f32_16x16x32_bf16(a1h, w1l, acc[1][1], 0, 0, 0);
    acc[G2][0] = __builtin_amdgcn_mfma_f32_16x16x32_bf16(a0h, w2l, acc[G2][0], 0, 0, 0);
    acc[G2][1] = __builtin_amdgcn_mfma_f32_16x16x32_bf16(a1h, w2l, acc[G2][1], 0, 0, 0);
    acc[0][0]  = __builtin_amdgcn_mfma_f32_16x16x32_bf16(a0l, w0h, acc[0][0], 0, 0, 0);
    acc[0][1]  = __builtin_amdgcn_mfma_f32_16x16x32_bf16(a1l, w0h, acc[0][1], 0, 0, 0);
    acc[1][0]  = __builtin_amdgcn_mfma_f32_16x16x32_bf16(a0l, w1h, acc[1][0], 0, 0, 0);
    acc[1][1]  = __builtin_amdgcn_mfma_f32_16x16x32_bf16(a1l, w1h, acc[1][1], 0, 0, 0);
    acc[G2][0] = __builtin_amdgcn_mfma_f32_16x16x32_bf16(a0l, w2h, acc[G2][0], 0, 0, 0);
    acc[G2][1] = __builtin_amdgcn_mfma_f32_16x16x32_bf16(a1l, w2h, acc[G2][1], 0, 0, 0);
}

// coalesced agent-coherent 16B fragment load (two 8B sc1 loads, no unpack)
__device__ __forceinline__ v8bf load_h8(const u16* p) {
    union { u64t d[2]; v8bf v; } u;
    const u64t* q = (const u64t*)p;
    u.d[0] = __hip_atomic_load(q,     __ATOMIC_RELAXED, __HIP_MEMORY_SCOPE_AGENT);
    u.d[1] = __hip_atomic_load(q + 1, __ATOMIC_RELAXED, __HIP_MEMORY_SCOPE_AGENT);
    return u.v;
}

// ---------------- persistent GRU recurrence, bf16x2 split precision ----------------
// grid = 256 = 4 batch-groups (gb, Mb=32) x 64 feature-groups (gn, Fb=16)
// block = 512 (8 waves, 2 waves/SIMD TLP). Wave w owns 2 x-chunks (w*2..w*2+1)
// and 4 h-chunks (w*4..w*4+3), whose producers are exactly gn=w*8..w*8+7.
// PROTOCOL FROZEN (round-2/7 verified): x phase FIRST, then per-wave poll, then
// sc1 h loads (rounds 3/5/6: flags visible before last data write-throughs ->
// reads must trail flag observation by ~1 x-phase).
// vs round 9:
//   (a) lo-plane weights LDS -> VGPR (18 v8bf = 72 regs/wave, wave-private &
//       loop-invariant). Deletes 144 ds_read_b128/block-step -- the residual
//       1.3e8 SQ_LDS_BANK_CONFLICT source and ~1700 cy/step of LDS pipe time.
//       LDS drops 156 KB -> ~9 KB.
//   (b) pin hA..hD right after the 4 HLOADs (asm "+v"): r9's VGPR=112 proves
//       the compiler sinks the loads toward use (live-range shrink), collapsing
//       the 4-deep LLC pipeline; the pin forces all 16 sc1 loads in flight.
// Math is bit-identical to round 9 (same MFMA order, same reduce order).
__launch_bounds__(512)
__global__ void k_gru(const u16* __restrict__ xpk,
                      const u16* __restrict__ Whi, const u16* __restrict__ Wlo,
                      u16* __restrict__ hpk,          // [2 parity][4 gb][32 chunk][2048]
                      unsigned* __restrict__ pf,      // [4][64] per-producer flags
                      const float* __restrict__ bi, const float* __restrict__ bhn,
                      float* __restrict__ dout) {
    __shared__ float accL[2304];                // 9 KB: 8 slots x (16 rows x 18 pad)
    const int tid = threadIdx.x;
    const int w = tid >> 6, l = tid & 63;       // w in 0..7
    const int gb = blockIdx.x >> 6, gn = blockIdx.x & 63;
    const int l15 = l & 15, q = l >> 4;

    // weight preload: hi AND lo planes -> VGPRs (wave-private, loop-invariant)
    v8bf whx[2][3], whh[4][3], wlx[2][3], wlh[4][3];
    #pragma unroll
    for (int j = 0; j < 2; j++)
        #pragma unroll
        for (int g = 0; g < 3; g++) {
            size_t roff = (size_t)(g * F + gn * 16 + l15) * KC + (F + (w * 2 + j) * 32) + q * 8;
            whx[j][g] = *(const v8bf*)(Whi + roff);
            wlx[j][g] = *(const v8bf*)(Wlo + roff);
        }
    #pragma unroll
    for (int j = 0; j < 4; j++)
        #pragma unroll
        for (int g = 0; g < 3; g++) {
            size_t roff = (size_t)(g * F + gn * 16 + l15) * KC + (w * 4 + j) * 32 + q * 8;
            whh[j][g] = *(const v8bf*)(Whi + roff);
            wlh[j][g] = *(const v8bf*)(Wlo + roff);
        }
    __syncthreads();

    // elementwise mapping (tid < 256 only): thread -> (mt, row, col-pair)
    const int mt_e = (tid >> 7) & 1;
    const int ii   = tid & 127;
    const int rl   = ii >> 3;            // 0..15
    const int cp   = (ii & 7) * 2;       // 0,2,..,14
    const int rowg = gb * 32 + mt_e * 16 + rl;
    const int c0g  = gn * 16 + cp;
    float bir0 = 0.f, bir1 = 0.f, biz0 = 0.f, biz1 = 0.f;
    float bin0 = 0.f, bin1 = 0.f, bh0 = 0.f, bh1 = 0.f;
    if (tid < 256) {
        bir0 = bi[c0g];         bir1 = bi[c0g + 1];
        biz0 = bi[F + c0g];     biz1 = bi[F + c0g + 1];
        bin0 = bi[2 * F + c0g]; bin1 = bi[2 * F + c0g + 1];
        bh0  = bhn[c0g];        bh1  = bhn[c0g + 1];
    }
    float hp0 = 0.f, hp1 = 0.f;
    // producer store address pieces (packed layout)
    const int st_kk   = c0g >> 5;
    const int st_q    = (c0g >> 3) & 3;
    const int st_e    = c0g & 7;
    const int st_lane = st_q * 16 + rl;
    const size_t st_off = (size_t)gb * 65536 + st_kk * 2048 + mt_e * 512 + st_lane * 8 + st_e;

    for (int t = 0; t < SEQ; t++) {
        v4f acc[4][2];
        #pragma unroll
        for (int gi = 0; gi < 4; gi++)
            #pragma unroll
            for (int mt = 0; mt < 2; mt++) {
                acc[gi][mt][0] = 0.f; acc[gi][mt][1] = 0.f;
                acc[gi][mt][2] = 0.f; acc[gi][mt][3] = 0.f;
            }

        // ---- 1. x phase: 2 chunks, plain cacheable demand loads (L2-shared) ----
        {
            const u16* xb = xpk + (size_t)(t * 4 + gb) * 32768;
            #pragma unroll
            for (int j = 0; j < 2; j++) {
                const u16* cb = xb + (w * 2 + j) * 2048 + l * 8;
                v8bf a0h = *(const v8bf*)(cb);
                v8bf a1h = *(const v8bf*)(cb + 512);
                v8bf a0l = *(const v8bf*)(cb + 1024);
                v8bf a1l = *(const v8bf*)(cb + 1536);
                do_chunk<3>(a0h, a1h, a0l, a1l,
                            whx[j][0], whx[j][1], whx[j][2],
                            wlx[j][0], wlx[j][1], wlx[j][2], acc);
            }
        }

        // ---- 2. per-wave poll AFTER x phase (frozen round-2 position; this
        //         wave's 8 producers only), then all 4 h-chunk loads in flight
        //         (pinned so the compiler cannot sink them to their use) ----
        if (t > 0) {
            {
                const unsigned* fp = pf + gb * 64 + w * 8 + (l & 7);
                unsigned tgt = (unsigned)t;
                long guard = 0;
                for (;;) {
                    unsigned v = __hip_atomic_load(fp, __ATOMIC_RELAXED, __HIP_MEMORY_SCOPE_AGENT);
                    if (__ballot(v < tgt) == 0ull) break;
                    __builtin_amdgcn_s_sleep(1);
                    if (++guard > 4000000L) break;
                }
            }
            asm volatile("" ::: "memory");   // no hoisting of loads above the poll
            const u16* hs = hpk + (size_t)((t & 1) ^ 1) * 262144 + (size_t)gb * 65536;
            v8bf hA[4], hB[4], hC[4], hD[4];
#define HLOAD(dst, jj) do { const u16* cb = hs + ((w * 4 + (jj)) * 2048) + l * 8; \
            dst[0] = load_h8(cb);        dst[1] = load_h8(cb + 512); \
            dst[2] = load_h8(cb + 1024); dst[3] = load_h8(cb + 1536); } while (0)
            HLOAD(hA, 0); HLOAD(hB, 1); HLOAD(hC, 2); HLOAD(hD, 3);
            // pin: keep all 16 sc1 loads issued here (4-deep LLC pipeline);
            // r9's VGPR=112 showed the compiler otherwise sinks them to use
            asm volatile(""
                : "+v"(hA[0]), "+v"(hA[1]), "+v"(hA[2]), "+v"(hA[3]),
                  "+v"(hB[0]), "+v"(hB[1]), "+v"(hB[2]), "+v"(hB[3]),
                  "+v"(hC[0]), "+v"(hC[1]), "+v"(hC[2]), "+v"(hC[3]),
                  "+v"(hD[0]), "+v"(hD[1]), "+v"(hD[2]), "+v"(hD[3]));
#define HSTEP(jj, buf) \
            do_chunk<2>(buf[0], buf[1], buf[2], buf[3], \
                        whh[jj][0], whh[jj][1], whh[jj][2], \
                        wlh[jj][0], wlh[jj][1], wlh[jj][2], acc)
            HSTEP(0, hA); HSTEP(1, hB); HSTEP(2, hC); HSTEP(3, hD);
#undef HSTEP
#undef HLOAD
        }

        // ---- 3. DETERMINISTIC cross-wave K-reduce, STATIC acc indexing.
        //      Round r: wave w handles slot s=(w+r)&7; r=0 overwrites, r>0 adds.
        //      Barrier between rounds -> slot s sums in FIXED wave order
        //      (s, s-1, ..., s+1 mod 8), replay-stable. s is WAVE-UNIFORM ->
        //      switch(s) is a scalar branch; compile-time acc indices keep acc
        //      in VGPRs (rule-#20). Stride 18: 2-way max bank aliasing (free). ----
#define RED_ONE(S) do { \
            float* p = &accL[(S) * 288 + q * 72 + l15]; \
            if (r == 0) { \
                p[0]  = acc[(S) >> 1][(S) & 1][0]; p[18] = acc[(S) >> 1][(S) & 1][1]; \
                p[36] = acc[(S) >> 1][(S) & 1][2]; p[54] = acc[(S) >> 1][(S) & 1][3]; \
            } else { \
                p[0]  += acc[(S) >> 1][(S) & 1][0]; p[18] += acc[(S) >> 1][(S) & 1][1]; \
                p[36] += acc[(S) >> 1][(S) & 1][2]; p[54] += acc[(S) >> 1][(S) & 1][3]; \
            } } while (0)
        #pragma unroll
        for (int r = 0; r < 8; r++) {
            const int s = (w + r) & 7;      // wave-uniform -> scalar branch
            switch (s) {
                case 0: RED_ONE(0); break;
                case 1: RED_ONE(1); break;
                case 2: RED_ONE(2); break;
                case 3: RED_ONE(3); break;
                case 4: RED_ONE(4); break;
                case 5: RED_ONE(5); break;
                case 6: RED_ONE(6); break;
                case 7: RED_ONE(7); break;
            }
            __syncthreads();
        }
#undef RED_ONE

        // ---- 4. fused elementwise (tid<256): thread owns (mt_e, rl, cols cp,cp+1) ----
        if (tid < 256) {
            u16* hd = hpk + (size_t)(t & 1) * 262144;
            int off = rl * 18 + cp;
            float pr0 = accL[(0 * 2 + mt_e) * 288 + off], pr1 = accL[(0 * 2 + mt_e) * 288 + off + 1];
            float pz0 = accL[(1 * 2 + mt_e) * 288 + off], pz1 = accL[(1 * 2 + mt_e) * 288 + off + 1];
            float ph0 = accL[(2 * 2 + mt_e) * 288 + off], ph1 = accL[(2 * 2 + mt_e) * 288 + off + 1];
            float px0 = accL[(3 * 2 + mt_e) * 288 + off], px1 = accL[(3 * 2 + mt_e) * 288 + off + 1];
            float r0 = sigm(pr0 + bir0), r1 = sigm(pr1 + bir1);
            float z0 = sigm(pz0 + biz0), z1 = sigm(pz1 + biz1);
            float n0 = tanh_fast(px0 + bin0 + r0 * (ph0 + bh0));
            float n1 = tanh_fast(px1 + bin1 + r1 * (ph1 + bh1));
            float hn0 = (1.f - z0) * n0 + z0 * hp0;
            float hn1 = (1.f - z1) * n1 + z1 * hp1;
            hp0 = hn0; hp1 = hn1;
            u16 h0 = f2bf(hn0), h1 = f2bf(hn1);
            u16 l0 = f2bf(hn0 - bf2f(h0)), l1 = f2bf(hn1 - bf2f(h1));
            unsigned hipair = (unsigned)h0 | ((unsigned)h1 << 16);
            unsigned lopair = (unsigned)l0 | ((unsigned)l1 << 16);
            __hip_atomic_store((unsigned*)(hd + st_off), hipair,
                               __ATOMIC_RELAXED, __HIP_MEMORY_SCOPE_AGENT);
            __hip_atomic_store((unsigned*)(hd + st_off + 1024), lopair,
                               __ATOMIC_RELAXED, __HIP_MEMORY_SCOPE_AGENT);
            if (t == SEQ - 1) {
                float2 o; o.x = hn0; o.y = hn1;
                *(float2*)(dout + 32768 + (size_t)rowg * F + c0g) = o;
            }
        }
        __threadfence_block();   // drain this wave's sc1 stores (vmcnt) without L2-wide ops
        __syncthreads();         // all waves drained
        if (tid == 0)
            __hip_atomic_store(pf + gb * 64 + gn, (unsigned)(t + 1),
                               __ATOMIC_RELAXED, __HIP_MEMORY_SCOPE_AGENT);
    }
}

// ---------------- output head: out[b][c] = carry[b] . Wo[:,c] + bo[c] (fp32 exact) ----------------
__global__ void k_head(const float* __restrict__ hf, const float* __restrict__ Wo,
                       const float* __restrict__ bo, float* __restrict__ dout) {
    int b = blockIdx.x, c = threadIdx.x;
    const float* h = hf + (size_t)b * F;
    float s = bo[c];
    #pragma unroll 4
    for (int k = 0; k < F; k++) s += h[k] * Wo[(size_t)k * OUTD + c];
    dout[(size_t)b * OUTD + c] = s;
}

extern "C" void kernel_launch(void* const* d_in, const int* in_sizes, int n_in,
                              void* d_out, int out_size, void* d_ws, size_t ws_size,
                              hipStream_t stream) {
    const float* inputs = (const float*)d_in[0];
    const float* Wi     = (const float*)d_in[1];
    const float* bi     = (const float*)d_in[2];
    const float* Wh     = (const float*)d_in[3];
    const float* bhn    = (const float*)d_in[4];
    const float* Wo     = (const float*)d_in[5];
    const float* bo     = (const float*)d_in[6];
    float* out = (float*)d_out;

    char* ws = (char*)d_ws;
    u16* xpk = (u16*)ws;                                  // 134,217,728 B (packed x, hi+lo)
    u16* Whi = (u16*)(ws + 134217728);                    //   9,437,184 B
    u16* Wlo = (u16*)(ws + 143654912);                    //   9,437,184 B
    u16* hpk = (u16*)(ws + 153092096);                    //   1,048,576 B (packed h)
    unsigned* pf = (unsigned*)(ws + 154140672);           //       1,024 B

    hipMemsetAsync(pf, 0, 4 * 64 * sizeof(unsigned), stream);

    k_prep_x<<<16384, 256, 0, stream>>>(inputs, xpk);
    k_prep_w<<<4608, 256, 0, stream>>>(Wi, Wh, Whi, Wlo);
    k_gru<<<256, 512, 0, stream>>>(xpk, Whi, Wlo, hpk, pf, bi, bhn, out);
    k_head<<<128, 256, 0, stream>>>(out + (size_t)BATCH * OUTD, Wo, bo, out);
}

// Round 11
// 3309.553 us; speedup vs baseline: 1.2591x; 1.2591x over previous
//
#include <hip/hip_runtime.h>
#include <hip/hip_bf16.h>
#include <math.h>

#define BATCH 128
#define SEQ   512
#define IND   512
#define F     1024
#define OUTD  256
// concat K = F + IND = 1536
#define KC    1536
#define N3    3072

typedef __bf16 v8bf __attribute__((ext_vector_type(8)));
typedef float  v4f  __attribute__((ext_vector_type(4)));
typedef unsigned short u16;
typedef u16 v8u __attribute__((ext_vector_type(8)));
typedef unsigned long long u64t;

// packed tile layout, shared by x and h:
//   [chunk][plane 2][mt 2][lane 64][8 elems]  (2048 elems per chunk)
// lane = q*16 + l15 maps to (row = mt*16 + l15, cols = chunk*32 + q*8 .. +7)

__device__ inline u16 f2bf(float x) {
    union { float f; unsigned u; } v; v.f = x;
    unsigned r = v.u + 0x7fff + ((v.u >> 16) & 1);
    return (u16)(r >> 16);
}
__device__ inline float bf2f(u16 h) {
    union { unsigned u; float f; } v; v.u = ((unsigned)h) << 16;
    return v.f;
}

__device__ inline float sigm(float x) { return 1.f / (1.f + __expf(-x)); }
__device__ inline float tanh_fast(float x) {
    float xc = fminf(fmaxf(x, -15.f), 15.f);
    float e = __expf(2.f * xc);
    return (e - 1.f) / (e + 1.f);
}

// ---------------- prep: inputs [B][T][I] fp32 -> packed x tiles ----------------
// xpk[t][gb][chunk 0..15][plane][mt][lane][8]
__global__ void k_prep_x(const float* __restrict__ in, u16* __restrict__ xpk) {
    int gid = blockIdx.x * 256 + threadIdx.x;     // 4,194,304 chunks of 8
    int b = gid >> 15;
    int rem = gid & 32767;
    int t = rem >> 6;
    int c = rem & 63;                              // 8-col segment index
    const float* s = in + (size_t)gid * 8;
    float4 a0 = ((const float4*)s)[0];
    float4 a1 = ((const float4*)s)[1];
    float a[8] = {a0.x, a0.y, a0.z, a0.w, a1.x, a1.y, a1.z, a1.w};
    v8u oh, ol;
    #pragma unroll
    for (int i = 0; i < 8; i++) {
        u16 h = f2bf(a[i]);
        oh[i] = h;
        ol[i] = f2bf(a[i] - bf2f(h));
    }
    int gb = b >> 5, mt = (b >> 4) & 1, l15 = b & 15;
    int chunk = c >> 2, q = c & 3;
    int lane = q * 16 + l15;
    size_t base = ((size_t)(t * 4 + gb) * 16 + chunk) * 2048 + mt * 512 + lane * 8;
    *(v8u*)(xpk + base) = oh;            // plane 0 (hi)
    *(v8u*)(xpk + base + 1024) = ol;     // plane 1 (lo)
}

// ------------- prep: WcT[n][k] hi/lo bf16 planes, n in [0,3072), k in [0,1536) --------------
__global__ void k_prep_w(const float* __restrict__ Wi, const float* __restrict__ Wh,
                         u16* __restrict__ Whi, u16* __restrict__ Wlo) {
    __shared__ float lds[32][33];
    int nb = blockIdx.x % 96;      // 3072/32
    int kb = blockIdx.x / 96;      // 1536/32
    int tid = threadIdx.x;
    int n_l = tid & 31, kr = tid >> 5;
    #pragma unroll
    for (int j = 0; j < 4; j++) {
        int k_l = kr + j * 8;
        int k = kb * 32 + k_l, n = nb * 32 + n_l;
        float v = (k < F) ? Wh[(size_t)k * N3 + n] : Wi[(size_t)(k - F) * N3 + n];
        lds[k_l][n_l] = v;
    }
    __syncthreads();
    int k_l2 = tid & 31, nr = tid >> 5;
    #pragma unroll
    for (int j = 0; j < 4; j++) {
        int n_l2 = nr + j * 8;
        float v = lds[k_l2][n_l2];
        u16 h = f2bf(v);
        size_t off = (size_t)(nb * 32 + n_l2) * KC + kb * 32 + k_l2;
        Whi[off] = h;
        Wlo[off] = f2bf(v - bf2f(h));
    }
}

// one K-chunk: 18 MFMAs, lo-plane weights from LDS (r9-proven variant)
template<int G2>
__device__ __forceinline__ void do_chunk(v8bf a0h, v8bf a1h, v8bf a0l, v8bf a1l,
                                         v8bf w0h, v8bf w1h, v8bf w2h,
                                         const u16* wlo, v4f (&acc)[4][2]) {
    v8bf w0l = *(const v8bf*)(wlo);
    v8bf w1l = *(const v8bf*)(wlo + 512);
    v8bf w2l = *(const v8bf*)(wlo + 1024);
    acc[0][0]  = __builtin_amdgcn_mfma_f32_16x16x32_bf16(a0h, w0h, acc[0][0], 0, 0, 0);
    acc[0][1]  = __builtin_amdgcn_mfma_f32_16x16x32_bf16(a1h, w0h, acc[0][1], 0, 0, 0);
    acc[1][0]  = __builtin_amdgcn_mfma_f32_16x16x32_bf16(a0h, w1h, acc[1][0], 0, 0, 0);
    acc[1][1]  = __builtin_amdgcn_mfma_f32_16x16x32_bf16(a1h, w1h, acc[1][1], 0, 0, 0);
    acc[G2][0] = __builtin_amdgcn_mfma_f32_16x16x32_bf16(a0h, w2h, acc[G2][0], 0, 0, 0);
    acc[G2][1] = __builtin_amdgcn_mfma_f32_16x16x32_bf16(a1h, w2h, acc[G2][1], 0, 0, 0);
    acc[0][0]  = __builtin_amdgcn_mfma_f32_16x16x32_bf16(a0h, w0l, acc[0][0], 0, 0, 0);
    acc[0][1]  = __builtin_amdgcn_mfma_f32_16x16x32_bf16(a1h, w0l, acc[0][1], 0, 0, 0);
    acc[1][0]  = __builtin_amdgcn_mfma_f32_16x16x32_bf16(a0h, w1l, acc[1][0], 0, 0, 0);
    acc[1][1]  = __builtin_amdgcn_mfma_f32_16x16x32_bf16(a1h, w1l, acc[1][1], 0, 0, 0);
    acc[G2][0] = __builtin_amdgcn_mfma_f32_16x16x32_bf16(a0h, w2l, acc[G2][0], 0, 0, 0);
    acc[G2][1] = __builtin_amdgcn_mfma_f32_16x16x32_bf16(a1h, w2l, acc[G2][1], 0, 0, 0);
    acc[0][0]  = __builtin_amdgcn_mfma_f32_16x16x32_bf16(a0l, w0h, acc[0][0], 0, 0, 0);
    acc[0][1]  = __builtin_amdgcn_mfma_f32_16x16x32_bf16(a1l, w0h, acc[0][1], 0, 0, 0);
    acc[1][0]  = __builtin_amdgcn_mfma_f32_16x16x32_bf16(a0l, w1h, acc[1][0], 0, 0, 0);
    acc[1][1]  = __builtin_amdgcn_mfma_f32_16x16x32_bf16(a1l, w1h, acc[1][1], 0, 0, 0);
    acc[G2][0] = __builtin_amdgcn_mfma_f32_16x16x32_bf16(a0l, w2h, acc[G2][0], 0, 0, 0);
    acc[G2][1] = __builtin_amdgcn_mfma_f32_16x16x32_bf16(a1l, w2h, acc[G2][1], 0, 0, 0);
}

// register-lo variant (only for the single x-chunk whose lo plane moved to VGPR)
template<int G2>
__device__ __forceinline__ void do_chunk_reg(v8bf a0h, v8bf a1h, v8bf a0l, v8bf a1l,
                                             v8bf w0h, v8bf w1h, v8bf w2h,
                                             v8bf w0l, v8bf w1l, v8bf w2l,
                                             v4f (&acc)[4][2]) {
    acc[0][0]  = __builtin_amdgcn_mfma_f32_16x16x32_bf16(a0h, w0h, acc[0][0], 0, 0, 0);
    acc[0][1]  = __builtin_amdgcn_mfma_f32_16x16x32_bf16(a1h, w0h, acc[0][1], 0, 0, 0);
    acc[1][0]  = __builtin_amdgcn_mfma_f32_16x16x32_bf16(a0h, w1h, acc[1][0], 0, 0, 0);
    acc[1][1]  = __builtin_amdgcn_mfma_f32_16x16x32_bf16(a1h, w1h, acc[1][1], 0, 0, 0);
    acc[G2][0] = __builtin_amdgcn_mfma_f32_16x16x32_bf16(a0h, w2h, acc[G2][0], 0, 0, 0);
    acc[G2][1] = __builtin_amdgcn_mfma_f32_16x16x32_bf16(a1h, w2h, acc[G2][1], 0, 0, 0);
    acc[0][0]  = __builtin_amdgcn_mfma_f32_16x16x32_bf16(a0h, w0l, acc[0][0], 0, 0, 0);
    acc[0][1]  = __builtin_amdgcn_mfma_f32_16x16x32_bf16(a1h, w0l, acc[0][1], 0, 0, 0);
    acc[1][0]  = __builtin_amdgcn_mfma_f32_16x16x32_bf16(a0h, w1l, acc[1][0], 0, 0, 0);
    acc[1][1]  = __builtin_amdgcn_mfma_f32_16x16x32_bf16(a1h, w1l, acc[1][1], 0, 0, 0);
    acc[G2][0] = __builtin_amdgcn_mfma_f32_16x16x32_bf16(a0h, w2l, acc[G2][0], 0, 0, 0);
    acc[G2][1] = __builtin_amdgcn_mfma_f32_16x16x32_bf16(a1h, w2l, acc[G2][1], 0, 0, 0);
    acc[0][0]  = __builtin_amdgcn_mfma_f32_16x16x32_bf16(a0l, w0h, acc[0][0], 0, 0, 0);
    acc[0][1]  = __builtin_amdgcn_mfma_f32_16x16x32_bf16(a1l, w0h, acc[0][1], 0, 0, 0);
    acc[1][0]  = __builtin_amdgcn_mfma_f32_16x16x32_bf16(a0l, w1h, acc[1][0], 0, 0, 0);
    acc[1][1]  = __builtin_amdgcn_mfma_f32_16x16x32_bf16(a1l, w1h, acc[1][1], 0, 0, 0);
    acc[G2][0] = __builtin_amdgcn_mfma_f32_16x16x32_bf16(a0l, w2h, acc[G2][0], 0, 0, 0);
    acc[G2][1] = __builtin_amdgcn_mfma_f32_16x16x32_bf16(a1l, w2h, acc[G2][1], 0, 0, 0);
}

// coalesced agent-coherent 16B fragment load (two 8B sc1 loads, no unpack)
__device__ __forceinline__ v8bf load_h8(const u16* p) {
    union { u64t d[2]; v8bf v; } u;
    const u64t* q = (const u64t*)p;
    u.d[0] = __hip_atomic_load(q,     __ATOMIC_RELAXED, __HIP_MEMORY_SCOPE_AGENT);
    u.d[1] = __hip_atomic_load(q + 1, __ATOMIC_RELAXED, __HIP_MEMORY_SCOPE_AGENT);
    return u.v;
}

// ---------------- persistent GRU recurrence, bf16x2 split precision ----------------
// grid = 256 = 4 gb x 64 gn; block = 512 (8 waves, 2/SIMD). Wave w: 2 x-chunks,
// 4 h-chunks (producers gn=w*8..w*8+7). PROTOCOL (r2/7/9-frozen core): x phase
// FIRST, then per-wave poll, then sc1 h loads (read-late guards the flag/data
// visibility window). Round-11 tail-split:
//   (a) elementwise on ALL 8 waves (1 col/thread) -- tail latency halves
//   (b) PER-WAVE flags pf[gb][gn][8]: each wave drains its OWN sc1 stores
//       (threadfence_block = own vmcnt) and posts its own flag; the final
//       block barrier is gone -- waves flow into step t+1's x phase.
//       Consumer wave w polls 64 flags (8 producers x 8 waves) on 64 lanes.
//       Overwrite safety: any wave-flag(t+2) implies that block passed its
//       step-t+1 reduce barriers, hence finished ALL h(t+1) reads.
//   (c) accL parity double-buffer (2 x 9 KB) kills the cross-step WAR on the
//       reduce scratch; funded by moving x-lo chunk j=0 to VGPR (12 regs/wave,
//       LDS 144->120 KB for wloL; total 141 KB).
// Reduce order and all arithmetic bit-identical to round 9.
__launch_bounds__(512)
__global__ void k_gru(const u16* __restrict__ xpk,
                      const u16* __restrict__ Whi, const u16* __restrict__ Wlo,
                      u16* __restrict__ hpk,          // [2 parity][4 gb][32 chunk][2048]
                      unsigned* __restrict__ pf,      // [4 gb][64 gn][8 wave] flags
                      const float* __restrict__ bi, const float* __restrict__ bhn,
                      float* __restrict__ dout) {
    __shared__ __align__(16) u16 wloL[61440];   // 120 KB: [8 w][5 slots][3 gates][512]
    __shared__ float accL[4608];                // 18 KB: [2 parity][8 slots][16 rows x 18]
    const int tid = threadIdx.x;
    const int w = tid >> 6, l = tid & 63;       // w in 0..7
    const int gb = blockIdx.x >> 6, gn = blockIdx.x & 63;
    const int l15 = l & 15, q = l >> 4;

    // weight preload: hi -> VGPR; lo -> LDS except x-chunk j=0 (VGPR, 12 regs)
    v8bf whx[2][3], whh[4][3], wlx0[3];
    #pragma unroll
    for (int j = 0; j < 2; j++)
        #pragma unroll
        for (int g = 0; g < 3; g++) {
            size_t roff = (size_t)(g * F + gn * 16 + l15) * KC + (F + (w * 2 + j) * 32) + q * 8;
            whx[j][g] = *(const v8bf*)(Whi + roff);
            if (j == 0) wlx0[g] = *(const v8bf*)(Wlo + roff);
            else *(v8u*)(&wloL[(((w * 5 + 4) * 3 + g) << 9) + l * 8]) = *(const v8u*)(Wlo + roff);
        }
    #pragma unroll
    for (int j = 0; j < 4; j++)
        #pragma unroll
        for (int g = 0; g < 3; g++) {
            size_t roff = (size_t)(g * F + gn * 16 + l15) * KC + (w * 4 + j) * 32 + q * 8;
            whh[j][g] = *(const v8bf*)(Whi + roff);
            *(v8u*)(&wloL[(((w * 5 + j) * 3 + g) << 9) + l * 8]) = *(const v8u*)(Wlo + roff);
        }
    __syncthreads();

    // elementwise mapping (ALL 512 threads, 1 column each):
    // wave w covers mt = w>>2, rows (w&3)*4 + (l>>4), col = l&15
    const int colL = l & 15;
    const int rowL = (w & 3) * 4 + (l >> 4);     // 0..15 within mt half
    const int mt_e = w >> 2;                     // 0/1
    const int rowg = gb * 32 + mt_e * 16 + rowL;
    const int c0g  = gn * 16 + colL;
    const float birC = bi[c0g];
    const float bizC = bi[F + c0g];
    const float binC = bi[2 * F + c0g];
    const float bhC  = bhn[c0g];
    float hp = 0.f;
    // producer store address (packed layout), 1 u16 hi + 1 u16 lo per thread
    const int st_kk   = c0g >> 5;
    const int st_q    = (c0g >> 3) & 3;
    const int st_e    = c0g & 7;
    const size_t st_off = (size_t)gb * 65536 + st_kk * 2048 + mt_e * 512
                        + (st_q * 16 + rowL) * 8 + st_e;

    for (int t = 0; t < SEQ; t++) {
        v4f acc[4][2];
        #pragma unroll
        for (int gi = 0; gi < 4; gi++)
            #pragma unroll
            for (int mt = 0; mt < 2; mt++) {
                acc[gi][mt][0] = 0.f; acc[gi][mt][1] = 0.f;
                acc[gi][mt][2] = 0.f; acc[gi][mt][3] = 0.f;
            }

        // ---- 1. x phase: 2 chunks (j=0 reg-lo, j=1 LDS-lo) ----
        {
            const u16* xb = xpk + (size_t)(t * 4 + gb) * 32768;
            {
                const u16* cb = xb + (w * 2 + 0) * 2048 + l * 8;
                v8bf a0h = *(const v8bf*)(cb);
                v8bf a1h = *(const v8bf*)(cb + 512);
                v8bf a0l = *(const v8bf*)(cb + 1024);
                v8bf a1l = *(const v8bf*)(cb + 1536);
                do_chunk_reg<3>(a0h, a1h, a0l, a1l,
                                whx[0][0], whx[0][1], whx[0][2],
                                wlx0[0], wlx0[1], wlx0[2], acc);
            }
            {
                const u16* cb = xb + (w * 2 + 1) * 2048 + l * 8;
                v8bf a0h = *(const v8bf*)(cb);
                v8bf a1h = *(const v8bf*)(cb + 512);
                v8bf a0l = *(const v8bf*)(cb + 1024);
                v8bf a1l = *(const v8bf*)(cb + 1536);
                do_chunk<3>(a0h, a1h, a0l, a1l,
                            whx[1][0], whx[1][1], whx[1][2],
                            &wloL[(((w * 5 + 4) * 3) << 9) + l * 8], acc);
            }
        }

        // ---- 2. per-wave poll AFTER x phase (64 flags = 8 producers x 8 waves),
        //         then all 4 h-chunk loads upfront, sc1 ----
        if (t > 0) {
            {
                const unsigned* fp = pf + gb * 512 + (w * 8 + (l >> 3)) * 8 + (l & 7);
                unsigned tgt = (unsigned)t;
                long guard = 0;
                for (;;) {
                    unsigned v = __hip_atomic_load(fp, __ATOMIC_RELAXED, __HIP_MEMORY_SCOPE_AGENT);
                    if (__ballot(v < tgt) == 0ull) break;
                    __builtin_amdgcn_s_sleep(1);
                    if (++guard > 4000000L) break;
                }
            }
            asm volatile("" ::: "memory");   // no hoisting of loads above the poll
            const u16* hs = hpk + (size_t)((t & 1) ^ 1) * 262144 + (size_t)gb * 65536;
            v8bf hA[4], hB[4], hC[4], hD[4];
#define HLOAD(dst, jj) do { const u16* cb = hs + ((w * 4 + (jj)) * 2048) + l * 8; \
            dst[0] = load_h8(cb);        dst[1] = load_h8(cb + 512); \
            dst[2] = load_h8(cb + 1024); dst[3] = load_h8(cb + 1536); } while (0)
            HLOAD(hA, 0); HLOAD(hB, 1); HLOAD(hC, 2); HLOAD(hD, 3);
#define HSTEP(jj, buf) \
            do_chunk<2>(buf[0], buf[1], buf[2], buf[3], \
                        whh[jj][0], whh[jj][1], whh[jj][2], \
                        &wloL[(((w * 5 + (jj)) * 3) << 9) + l * 8], acc)
            HSTEP(0, hA); HSTEP(1, hB); HSTEP(2, hC); HSTEP(3, hD);
#undef HSTEP
#undef HLOAD
        }

        // ---- 3. DETERMINISTIC cross-wave K-reduce (r9 order, parity dbuf).
        //      Round r: wave w handles slot s=(w+r)&7; r=0 overwrites, r>0 adds.
        //      Fixed per-slot wave order (s, s-1, ..., s+1 mod 8) -> replay-stable.
        //      switch(s) keeps acc indices compile-time (rule #20). ----
        float* ac = &accL[(t & 1) * 2304];
#define RED_ONE(S) do { \
            float* p = ac + (S) * 288 + q * 72 + l15; \
            if (r == 0) { \
                p[0]  = acc[(S) >> 1][(S) & 1][0]; p[18] = acc[(S) >> 1][(S) & 1][1]; \
                p[36] = acc[(S) >> 1][(S) & 1][2]; p[54] = acc[(S) >> 1][(S) & 1][3]; \
            } else { \
                p[0]  += acc[(S) >> 1][(S) & 1][0]; p[18] += acc[(S) >> 1][(S) & 1][1]; \
                p[36] += acc[(S) >> 1][(S) & 1][2]; p[54] += acc[(S) >> 1][(S) & 1][3]; \
            } } while (0)
        #pragma unroll
        for (int r = 0; r < 8; r++) {
            const int s = (w + r) & 7;      // wave-uniform -> scalar branch
            switch (s) {
                case 0: RED_ONE(0); break;
                case 1: RED_ONE(1); break;
                case 2: RED_ONE(2); break;
                case 3: RED_ONE(3); break;
                case 4: RED_ONE(4); break;
                case 5: RED_ONE(5); break;
                case 6: RED_ONE(6); break;
                case 7: RED_ONE(7); break;
            }
            __syncthreads();
        }
#undef RED_ONE

        // ---- 4. fused elementwise on ALL waves (1 col/thread), per-wave tail:
        //         own stores -> own vmcnt drain -> own flag. No block barrier. ----
        {
            u16* hd = hpk + (size_t)(t & 1) * 262144;
            const int off = rowL * 18 + colL;
            float pr = ac[(0 * 2 + mt_e) * 288 + off];
            float pz = ac[(1 * 2 + mt_e) * 288 + off];
            float ph = ac[(2 * 2 + mt_e) * 288 + off];
            float px = ac[(3 * 2 + mt_e) * 288 + off];
            float rg = sigm(pr + birC);
            float zg = sigm(pz + bizC);
            float ng = tanh_fast(px + binC + rg * (ph + bhC));
            float hn = (1.f - zg) * ng + zg * hp;
            hp = hn;
            u16 hh = f2bf(hn);
            u16 ll = f2bf(hn - bf2f(hh));
            __hip_atomic_store(hd + st_off, hh,
                               __ATOMIC_RELAXED, __HIP_MEMORY_SCOPE_AGENT);
            __hip_atomic_store(hd + st_off + 1024, ll,
                               __ATOMIC_RELAXED, __HIP_MEMORY_SCOPE_AGENT);
            if (t == SEQ - 1)
                dout[32768 + (size_t)rowg * F + c0g] = hn;
        }
        __threadfence_block();   // drain THIS wave's sc1 stores (own vmcnt)
        if (l == 0)
            __hip_atomic_store(pf + gb * 512 + gn * 8 + w, (unsigned)(t + 1),
                               __ATOMIC_RELAXED, __HIP_MEMORY_SCOPE_AGENT);
        // no block barrier: waves flow into step t+1's x phase; the reduce
        // barriers of t+1 re-sync, and accL parity removes the WAR hazard.
    }
}

// ---------------- output head: out[b][c] = carry[b] . Wo[:,c] + bo[c] (fp32 exact) ----------------
__global__ void k_head(const float* __restrict__ hf, const float* __restrict__ Wo,
                       const float* __restrict__ bo, float* __restrict__ dout) {
    int b = blockIdx.x, c = threadIdx.x;
    const float* h = hf + (size_t)b * F;
    float s = bo[c];
    #pragma unroll 4
    for (int k = 0; k < F; k++) s += h[k] * Wo[(size_t)k * OUTD + c];
    dout[(size_t)b * OUTD + c] = s;
}

extern "C" void kernel_launch(void* const* d_in, const int* in_sizes, int n_in,
                              void* d_out, int out_size, void* d_ws, size_t ws_size,
                              hipStream_t stream) {
    const float* inputs = (const float*)d_in[0];
    const float* Wi     = (const float*)d_in[1];
    const float* bi     = (const float*)d_in[2];
    const float* Wh     = (const float*)d_in[3];
    const float* bhn    = (const float*)d_in[4];
    const float* Wo     = (const float*)d_in[5];
    const float* bo     = (const float*)d_in[6];
    float* out = (float*)d_out;

    char* ws = (char*)d_ws;
    u16* xpk = (u16*)ws;                                  // 134,217,728 B (packed x, hi+lo)
    u16* Whi = (u16*)(ws + 134217728);                    //   9,437,184 B
    u16* Wlo = (u16*)(ws + 143654912);                    //   9,437,184 B
    u16* hpk = (u16*)(ws + 153092096);                    //   1,048,576 B (packed h)
    unsigned* pf = (unsigned*)(ws + 154140672);           //       8,192 B ([4][64][8] flags)

    hipMemsetAsync(pf, 0, 4 * 64 * 8 * sizeof(unsigned), stream);

    k_prep_x<<<16384, 256, 0, stream>>>(inputs, xpk);
    k_prep_w<<<4608, 256, 0, stream>>>(Wi, Wh, Whi, Wlo);
    k_gru<<<256, 512, 0, stream>>>(xpk, Whi, Wlo, hpk, pf, bi, bhn, out);
    k_head<<<128, 256, 0, stream>>>(out + (size_t)BATCH * OUTD, Wo, bo, out);
}